// Round 6
// baseline (618.310 us; speedup 1.0000x reference)
//
#include <hip/hip_runtime.h>

using short8 = __attribute__((ext_vector_type(8))) short;
using f32x16 = __attribute__((ext_vector_type(16))) float;

#define THR_LOGIT (-1.0986122886681098f)   // ln(1/3): sigmoid(x)>0.25 <=> x>ln(1/3)

__device__ __forceinline__ unsigned short f2bf(float f) {
  unsigned u = __float_as_uint(f);
  u = (u + 0x7FFFu + ((u >> 16) & 1u)) >> 16;   // RNE
  return (unsigned short)u;
}

__device__ __forceinline__ void async_copy16(void* lds, const void* g) {
  __builtin_amdgcn_global_load_lds(
      (const __attribute__((address_space(1))) unsigned int*)g,
      (__attribute__((address_space(3))) unsigned int*)lds, 16, 0, 0);
}

// ---------------- prep: weight transposes ----------------
// wt2: [co(4)][tap(27)][ks(2)][half(2)][l31(32)][8c] bf16 (110592 shorts)
__global__ void __launch_bounds__(256) k_prep(const float* __restrict__ c1w,
    const float* __restrict__ pw1, const float* __restrict__ pw2,
    short* __restrict__ wt2, float* __restrict__ w1t, float* __restrict__ w2t) {
  int i = blockIdx.x * 256 + threadIdx.x;
  if (i < 110592) {
    int j8 = i & 7, l31v = (i >> 3) & 31, halfv = (i >> 8) & 1, ksv = (i >> 9) & 1;
    int tapco = i >> 10;                 // 0..107
    int tap = tapco % 27, co = tapco / 27;
    int c = co * 32 + ksv * 16 + halfv * 8 + j8;
    wt2[i] = (short)f2bf(c1w[l31v * 3456 + c * 27 + tap]);
  } else if (i < 126976) {
    int i2 = i - 110592; int c = i2 >> 7; int j = i2 & 127;
    w1t[i2] = pw1[j * 128 + c];
  } else if (i < 135168) {
    int i3 = i - 126976; int j = i3 >> 6; int d = i3 & 63;
    w2t[i3] = pw2[d * 128 + j];
  }
}

__global__ void k_inv(const int* __restrict__ vidx, int* __restrict__ inv) {
  int t = threadIdx.x;
  for (int k = t; k < 4096; k += 256) inv[k] = -1;
  __syncthreads();
  if (t < 100) inv[vidx[t]] = t;
}

// ---------------- stage: transpose->bf16 [b][z][y][co][x][32c] (pre-swizzled granules),
// patch sums, voxel gather ----
__global__ void __launch_bounds__(256) k_stage(const float* __restrict__ src,
    short* __restrict__ in2, float* __restrict__ S4, float* __restrict__ Xmat,
    const int* __restrict__ inv, int vox_row_base) {
  __shared__ float tile[128][65];
  __shared__ int mcnt;
  __shared__ int mx[64];
  __shared__ int mrow[64];
  int bi = blockIdx.x;
  int b = bi >> 8, z = (bi >> 2) & 63, yp = bi & 3;
  int t = threadIdx.x;
  int zp = z >> 4, pz = z & 15;
  int cc = t & 127, xh = t >> 7;
  float part0 = 0.f, part1 = 0.f;

  for (int y0 = 0; y0 < 16; ++y0) {
    int y = yp * 16 + y0;
    __syncthreads();
    if (t == 0) mcnt = 0;
    {
      int x = t & 63, w = t >> 6;
      const float* sp = src + (long)b * 128 * 262144 + (long)z * 4096 + (long)y * 64 + x;
      #pragma unroll 4
      for (int it = 0; it < 32; ++it) {
        int c = it * 4 + w;
        tile[c][x] = sp[(long)c * 262144];
      }
    }
    __syncthreads();
    if (in2 != nullptr) {
      long rowbase = ((long)(b * 64 + z) * 64 + y) * 8192;
      int x = t >> 2, kg = t & 3;
      int slot = kg ^ ((x >> 1) & 3);
      #pragma unroll
      for (int co = 0; co < 4; ++co) {
        short8 pk;
        #pragma unroll
        for (int j = 0; j < 8; ++j) pk[j] = (short)f2bf(tile[co * 32 + kg * 8 + j][x]);
        *(short8*)(in2 + rowbase + co * 2048 + x * 32 + slot * 8) = pk;
      }
    }
    {
      float s0 = 0.f, s1 = 0.f;
      #pragma unroll
      for (int px = 0; px < 16; ++px) s0 += tile[cc][(xh * 2) * 16 + px];
      #pragma unroll
      for (int px = 0; px < 16; ++px) s1 += tile[cc][(xh * 2 + 1) * 16 + px];
      part0 += s0; part1 += s1;
    }
    if (t < 64) {
      int s = inv[pz * 256 + y0 * 16 + (t & 15)];
      if (s >= 0) {
        int idx = atomicAdd(&mcnt, 1);
        mx[idx] = t;
        int n = zp * 16 + yp * 4 + (t >> 4);
        mrow[idx] = vox_row_base + (b * 64 + n) * 100 + s;
      }
    }
    __syncthreads();
    int mc = mcnt;
    for (int i = 0; i < mc; ++i) {
      if (t < 128) Xmat[(long)mrow[i] * 128 + t] = tile[t][mx[i]];
    }
  }
  long sb = ((long)(b * 64 + z) * 4 + yp) * 512;
  S4[sb + cc * 4 + xh * 2 + 0] = part0;
  S4[sb + cc * 4 + xh * 2 + 1] = part1;
}

// ---------------- conv: 512thr, wave=(xh,kw,yh), T14 reg-prefetch of next window ----
// grid 2048 (XCD-swizzled): b(2) x z(64) x yg(16); 8 waves.
// wave: 32x (xh) x 32och x 2y (yh) x 1z, K-half ks=kw. Per tap: 1 B + 2 ds_read + 2 MFMA.
// LDS: 18 window rows x 4KB + zero row = 76 KB -> 2 blocks/CU (16 waves).
// co=0 staged via global_load_lds; co=1..3 prefetched to regs during compute (T14).
__global__ void __launch_bounds__(512, 4) k_conv(const short* __restrict__ in2,
    const short* __restrict__ wt2, const float* __restrict__ c1b,
    const float* __restrict__ c2w, const float* __restrict__ c2b,
    const short* __restrict__ zpage, int* __restrict__ counts) {
  extern __shared__ char smem[];
  __shared__ int lcnt[4];
  int bi0 = blockIdx.x;
  int bi = ((bi0 & 7) << 8) | (bi0 >> 3);          // bijective XCD swizzle (2048 = 8*256)
  int b = bi >> 10, z = (bi >> 4) & 63, yg = bi & 15;
  int y0 = yg * 4;
  int tid = threadIdx.x;
  int lane = tid & 63;
  int l31 = lane & 31, half = lane >> 5;
  int wave = tid >> 6;
  int xh = wave & 1, kw = (wave >> 1) & 1, yh = wave >> 2;
  const short8 zer = {};

  if (tid < 4) lcnt[tid] = 0;
  if (tid < 256) *(int4*)(smem + 73728 + tid * 16) = int4{0, 0, 0, 0};  // zero row
  int zoff = 73728 + lane * 16;

  // staging thread constants: chunk c covers rows wr = 2c + sr2
  int sr2 = tid >> 8, pos = tid & 255;
  // precompute per-chunk row base addresses (co=0) and validity
  long rowb[9];
  bool inb[9];
  #pragma unroll
  for (int c = 0; c < 9; ++c) {
    int wr = c * 2 + sr2;
    int zz = z - 1 + wr / 6;
    int yy = y0 - 1 + wr % 6;
    inb[c] = ((unsigned)zz < 64u) && ((unsigned)yy < 64u);
    rowb[c] = (((long)((b * 64 + zz) * 64 + yy)) * 4) * 2048 + pos * 8;
  }

  // A-fragment lane offsets per dx (ks fixed = kw)
  int xbase = xh * 32 + l31;
  int kg = kw * 2 + half;
  bool val[3];
  int offA[3];
  #pragma unroll
  for (int d = 0; d < 3; ++d) {
    int xp = xbase + d - 1;
    val[d] = (unsigned)xp < 64u;
    int xc = min(max(xp, 0), 63);
    offA[d] = xc * 64 + ((kg ^ ((xc >> 1) & 3)) << 4);
  }

  f32x16 acc0 = {}, acc1 = {};

  // ---- stage co=0 window via async global->LDS ----
  #pragma unroll
  for (int c = 0; c < 9; ++c) {
    const short* g = inb[c] ? (in2 + rowb[c]) : (zpage + pos * 8);
    async_copy16(smem + (c * 2 + sr2) * 4096 + pos * 16, g);
  }
  __syncthreads();   // drains vmcnt -> window 0 ready

  for (int co = 0; co < 4; ++co) {
    // ---- T14: prefetch next window into regs (in flight during compute) ----
    short8 st[9];
    if (co < 3) {
      #pragma unroll
      for (int c = 0; c < 9; ++c)
        st[c] = inb[c] ? *(const short8*)(in2 + rowb[c] + (co + 1) * 2048) : zer;
    }
    // ---- 27 taps, B 2-deep rotate, 2 MFMAs per tap (yh pair) ----
    const short8* pB = (const short8*)wt2 + co * 3456 + kw * 64 + half * 32 + l31;
    short8 bNext = pB[0];
    #pragma unroll
    for (int tap = 0; tap < 27; ++tap) {
      short8 bCur = bNext;
      if (tap < 26) bNext = pB[(tap + 1) * 128];
      const int dz = tap / 9, r9 = tap % 9, dy = r9 / 3, dxi = r9 % 3;
      bool v = val[dxi];
      int base = (dz * 6 + dy + yh * 2) * 4096 + offA[dxi];
      int ao0 = v ? base : zoff;
      int ao1 = v ? (base + 4096) : zoff;
      short8 a0 = *(const short8*)(smem + ao0);
      short8 a1 = *(const short8*)(smem + ao1);
      acc0 = __builtin_amdgcn_mfma_f32_32x32x16_bf16(a0, bCur, acc0, 0, 0, 0);
      acc1 = __builtin_amdgcn_mfma_f32_32x32x16_bf16(a1, bCur, acc1, 0, 0, 0);
    }
    __syncthreads();   // window free; also drains prefetch vmcnt
    if (co < 3) {
      #pragma unroll
      for (int c = 0; c < 9; ++c)
        *(short8*)(smem + (c * 2 + sr2) * 4096 + pos * 16) = st[c];
      __syncthreads();  // window co+1 ready
    }
  }

  // ---- cross-kw reduction via LDS (reuses window region) ----
  float* sf = (float*)smem;
  if (kw == 1) {
    #pragma unroll
    for (int r = 0; r < 16; ++r) {
      sf[(((xh * 2 + yh) * 2 + 0) * 16 + r) * 64 + lane] = acc0[r];
      sf[(((xh * 2 + yh) * 2 + 1) * 16 + r) * 64 + lane] = acc1[r];
    }
  }
  __syncthreads();
  if (kw == 0) {
    float b1v = c1b[l31];
    float w2v = c2w[l31];
    float b2v = c2b[0];
    int cnt0 = 0, cnt1 = 0;
    #pragma unroll
    for (int yi = 0; yi < 2; ++yi) {
      #pragma unroll
      for (int r = 0; r < 16; ++r) {
        float mine = yi ? acc1[r] : acc0[r];
        float v = mine + sf[(((xh * 2 + yh) * 2 + yi) * 16 + r) * 64 + lane];
        v = fmaxf(v + b1v, 0.f) * w2v;
        v += __shfl_xor(v, 1);
        v += __shfl_xor(v, 2);
        v += __shfl_xor(v, 4);
        v += __shfl_xor(v, 8);
        v += __shfl_xor(v, 16);
        int bit = (v + b2v) > THR_LOGIT;
        if (r < 8) cnt0 += bit; else cnt1 += bit;
      }
    }
    if (l31 == 0) {
      atomicAdd(&lcnt[xh * 2 + 0], cnt0);
      atomicAdd(&lcnt[xh * 2 + 1], cnt1);
    }
  }
  __syncthreads();
  if (tid < 4) {
    int n = (z >> 4) * 16 + (yg >> 2) * 4 + tid;
    atomicAdd(&counts[b * 64 + n], lcnt[tid]);
  }
}

// ---------------- reduce S4 -> X vec rows (deterministic) ----------------
__global__ void __launch_bounds__(256) k_vecreduce(const float* __restrict__ S4a,
    const float* __restrict__ S4p, float* __restrict__ Xmat) {
  int g = blockIdx.x * 256 + threadIdx.x;   // 32768
  int ten = g >> 14, rem = g & 16383;
  int b = rem >> 13, n = (rem >> 7) & 63, c = rem & 127;
  int zp = n >> 4, yp = (n >> 2) & 3, xp = n & 3;
  const float* S = ten ? S4p : S4a;
  float s = 0.f;
  #pragma unroll
  for (int k = 0; k < 16; ++k)
    s += S[((long)(b * 64 + zp * 16 + k) * 4 + yp) * 512 + c * 4 + xp];
  Xmat[(long)(ten * 128 + b * 64 + n) * 128 + c] = s * (1.f / 4096.f);
}

// ---------------- projector MLP + normalize ----------------
__global__ void __launch_bounds__(256) k_proj(const float* __restrict__ Xmat,
    const float* __restrict__ w1t, const float* __restrict__ pb1,
    const float* __restrict__ w2t, const float* __restrict__ pb2,
    float* __restrict__ P) {
  __shared__ float xsT[128][20];
  __shared__ float hsT[128][20];
  __shared__ float os[16][68];
  int bi = blockIdx.x;
  long row0 = (long)bi * 16;
  int t = threadIdx.x;
  {
    int r = t >> 4, c0 = (t & 15) * 8;
    const float* xp = Xmat + (row0 + r) * 128 + c0;
    #pragma unroll
    for (int k = 0; k < 8; ++k) xsT[c0 + k][r] = xp[k];
  }
  __syncthreads();
  {
    int j = t & 127, rh = t >> 7;
    float hacc[8];
    float bb = pb1[j];
    #pragma unroll
    for (int r8 = 0; r8 < 8; ++r8) hacc[r8] = bb;
    for (int c = 0; c < 128; ++c) {
      float w = w1t[c * 128 + j];
      float4 xlo = *(const float4*)&xsT[c][rh * 8];
      float4 xhi = *(const float4*)&xsT[c][rh * 8 + 4];
      hacc[0] += xlo.x * w; hacc[1] += xlo.y * w; hacc[2] += xlo.z * w; hacc[3] += xlo.w * w;
      hacc[4] += xhi.x * w; hacc[5] += xhi.y * w; hacc[6] += xhi.z * w; hacc[7] += xhi.w * w;
    }
    #pragma unroll
    for (int r8 = 0; r8 < 8; ++r8) hsT[j][rh * 8 + r8] = fmaxf(hacc[r8], 0.f);
  }
  __syncthreads();
  {
    int d = t & 63, rq = t >> 6;
    float oacc[4];
    float bb = pb2[d];
    #pragma unroll
    for (int r4 = 0; r4 < 4; ++r4) oacc[r4] = bb;
    for (int j = 0; j < 128; ++j) {
      float w = w2t[j * 64 + d];
      float4 hv = *(const float4*)&hsT[j][rq * 4];
      oacc[0] += hv.x * w; oacc[1] += hv.y * w; oacc[2] += hv.z * w; oacc[3] += hv.w * w;
    }
    #pragma unroll
    for (int r4 = 0; r4 < 4; ++r4) os[rq * 4 + r4][d] = oacc[r4];
  }
  __syncthreads();
  {
    int r = t >> 4, dg = t & 15;
    float4 v = *(const float4*)&os[r][dg * 4];
    float ss = v.x * v.x + v.y * v.y + v.z * v.z + v.w * v.w;
    ss += __shfl_xor(ss, 1); ss += __shfl_xor(ss, 2);
    ss += __shfl_xor(ss, 4); ss += __shfl_xor(ss, 8);
    float sc = 1.f / fmaxf(sqrtf(ss), 1e-12f);
    float4 o; o.x = v.x * sc; o.y = v.y * sc; o.z = v.z * sc; o.w = v.w * sc;
    *(float4*)&P[(row0 + r) * 64 + dg * 4] = o;
  }
}

// ---------------- sim + logsumexp per (b,n) ----------------
__global__ void __launch_bounds__(128) k_sim(const float* __restrict__ P,
                                             float* __restrict__ vloss) {
  __shared__ float ps[100][68];
  __shared__ float red[128];
  int bn = blockIdx.x;
  int t = threadIdx.x;
  long pbase = (long)(13056 + bn * 100) * 64;
  for (int i = t; i < 1600; i += 128) {
    int r = i >> 4, dg = i & 15;
    *(float4*)&ps[r][dg * 4] = *(const float4*)&P[pbase + r * 64 + dg * 4];
  }
  float4 areg[16];
  long abase = (long)(256 + bn * 100) * 64;
  if (t < 100) {
    #pragma unroll
    for (int j = 0; j < 16; ++j) areg[j] = *(const float4*)&P[abase + (long)t * 64 + j * 4];
  }
  __syncthreads();
  float res = 0.f;
  if (t < 100) {
    float m = -1e30f, sum = 0.f, diag = 0.f;
    for (int t2 = 0; t2 < 100; ++t2) {
      float d = 0.f;
      #pragma unroll
      for (int j = 0; j < 16; ++j) {
        float4 pv = *(const float4*)&ps[t2][j * 4];
        d += areg[j].x * pv.x + areg[j].y * pv.y + areg[j].z * pv.z + areg[j].w * pv.w;
      }
      float sim = d * 10.f;
      if (t2 == t) diag = sim;
      float nm = fmaxf(m, sim);
      sum = sum * __expf(m - nm) + __expf(sim - nm);
      m = nm;
    }
    res = m + logf(sum) - diag;
  }
  red[t] = res;
  __syncthreads();
  if (t == 0) {
    float s = 0.f;
    for (int i = 0; i < 100; ++i) s += red[i];
    vloss[bn] = s * 0.01f;
  }
}

// ---------------- final weighted reduction ----------------
__global__ void __launch_bounds__(128) k_final(const float* __restrict__ P,
    const float* __restrict__ vloss, const int* __restrict__ counts,
    const float* __restrict__ lw, float* __restrict__ out) {
  int t = threadIdx.x;
  int lane = t & 63;
  float pterm = 0.f, vterm = 0.f; int vcnt = 0;
  {
    int c = counts[t];
    bool maskv = c >= 2458;   // ratio > 0.6
    bool maskp = c <= 1638;   // ratio < 0.4
    float d = 0.f;
    for (int k = 0; k < 64; ++k) d += P[t * 64 + k] * P[(128 + t) * 64 + k];
    if (maskp) { pterm = -d * 10.f; vcnt += 1; }
    if (maskv) { vterm = vloss[t];  vcnt += 1; }
  }
  for (int m = 1; m < 64; m <<= 1) {
    pterm += __shfl_xor(pterm, m);
    vterm += __shfl_xor(vterm, m);
    vcnt  += __shfl_xor(vcnt, m);
  }
  __shared__ float sp[2], sv[2]; __shared__ int sc[2];
  if (lane == 0) { sp[t >> 6] = pterm; sv[t >> 6] = vterm; sc[t >> 6] = vcnt; }
  __syncthreads();
  if (t == 0) {
    float psum = sp[0] + sp[1], vsum = sv[0] + sv[1];
    int vc = sc[0] + sc[1];
    float total = lw[0] * psum + lw[1] * vsum;
    out[0] = (vc > 0) ? total / (float)vc : 0.f;
  }
}

// ---------------- launch ----------------
extern "C" void kernel_launch(void* const* d_in, const int* in_sizes, int n_in,
                              void* d_out, int out_size, void* d_ws, size_t ws_size,
                              hipStream_t stream) {
  const float* anchor   = (const float*)d_in[0];
  const float* positive = (const float*)d_in[1];
  const float* c1w = (const float*)d_in[2];
  const float* c1b = (const float*)d_in[3];
  const float* c2w = (const float*)d_in[4];
  const float* c2b = (const float*)d_in[5];
  const float* pw1 = (const float*)d_in[6];
  const float* pb1 = (const float*)d_in[7];
  const float* pw2 = (const float*)d_in[8];
  const float* pb2 = (const float*)d_in[9];
  const float* lw  = (const float*)d_in[10];
  const int*   vidx = (const int*)d_in[11];

  char* ws = (char*)d_ws;
  short* in2   = (short*)(ws + 0);                 // 134,217,728
  float* S4a   = (float*)(ws + 134217728);         // 1,048,576
  float* S4p   = (float*)(ws + 135266304);         // 1,048,576
  float* X     = (float*)(ws + 136314880);         // 13,238,272
  float* P     = (float*)(ws + 149553152);         // 6,619,136
  short* wt2   = (short*)(ws + 156172288);         // 221,184
  float* w1t   = (float*)(ws + 156393472);         // 65,536
  float* w2t   = (float*)(ws + 156459008);         // 32,768
  int*   inv   = (int*)  (ws + 156491776);         // 16,384
  int*   counts= (int*)  (ws + 156508160);         // 512
  float* vloss = (float*)(ws + 156508672);         // 512
  short* zpage = (short*)(ws + 156509184);         // 16,384 (zero page for OOB staging)

  hipFuncSetAttribute(reinterpret_cast<const void*>(k_conv),
                      hipFuncAttributeMaxDynamicSharedMemorySize, 77824);

  hipMemsetAsync(counts, 0, 128 * sizeof(int), stream);
  hipMemsetAsync(zpage, 0, 16384, stream);
  k_prep<<<528, 256, 0, stream>>>(c1w, pw1, pw2, wt2, w1t, w2t);
  k_inv<<<1, 256, 0, stream>>>(vidx, inv);
  k_stage<<<512, 256, 0, stream>>>(anchor,   in2,     S4a, X, inv, 256);
  k_stage<<<512, 256, 0, stream>>>(positive, nullptr, S4p, X, inv, 13056);
  k_conv<<<2048, 512, 77824, stream>>>(in2, wt2, c1b, c2w, c2b, zpage, counts);
  k_vecreduce<<<128, 256, 0, stream>>>(S4a, S4p, X);
  k_proj<<<1616, 256, 0, stream>>>(X, w1t, pb1, w2t, pb2, P);
  k_sim<<<128, 128, 0, stream>>>(P, vloss);
  k_final<<<1, 128, 0, stream>>>(P, vloss, counts, lw, (float*)d_out);
}

// Round 7
// 467.188 us; speedup vs baseline: 1.3235x; 1.3235x over previous
//
#include <hip/hip_runtime.h>

using short8 = __attribute__((ext_vector_type(8))) short;
using f32x16 = __attribute__((ext_vector_type(16))) float;

#define THR_LOGIT (-1.0986122886681098f)   // ln(1/3): sigmoid(x)>0.25 <=> x>ln(1/3)

__device__ __forceinline__ unsigned short f2bf(float f) {
  unsigned u = __float_as_uint(f);
  u = (u + 0x7FFFu + ((u >> 16) & 1u)) >> 16;   // RNE
  return (unsigned short)u;
}

__device__ __forceinline__ void async_copy16(void* lds, const void* g) {
  __builtin_amdgcn_global_load_lds(
      (const __attribute__((address_space(1))) unsigned int*)g,
      (__attribute__((address_space(3))) unsigned int*)lds, 16, 0, 0);
}

// ---------------- prep: weight transposes ----------------
// wt2: [co(4)][tap(27)][ks(2)][half(2)][l31(32)][8c] bf16 (110592 shorts)
__global__ void __launch_bounds__(256) k_prep(const float* __restrict__ c1w,
    const float* __restrict__ pw1, const float* __restrict__ pw2,
    short* __restrict__ wt2, float* __restrict__ w1t, float* __restrict__ w2t) {
  int i = blockIdx.x * 256 + threadIdx.x;
  if (i < 110592) {
    int j8 = i & 7, l31v = (i >> 3) & 31, halfv = (i >> 8) & 1, ksv = (i >> 9) & 1;
    int tapco = i >> 10;                 // 0..107
    int tap = tapco % 27, co = tapco / 27;
    int c = co * 32 + ksv * 16 + halfv * 8 + j8;
    wt2[i] = (short)f2bf(c1w[l31v * 3456 + c * 27 + tap]);
  } else if (i < 126976) {
    int i2 = i - 110592; int c = i2 >> 7; int j = i2 & 127;
    w1t[i2] = pw1[j * 128 + c];
  } else if (i < 135168) {
    int i3 = i - 126976; int j = i3 >> 6; int d = i3 & 63;
    w2t[i3] = pw2[d * 128 + j];
  }
}

__global__ void k_inv(const int* __restrict__ vidx, int* __restrict__ inv) {
  int t = threadIdx.x;
  for (int k = t; k < 4096; k += 256) inv[k] = -1;
  __syncthreads();
  if (t < 100) inv[vidx[t]] = t;
}

// ---------------- stage: transpose->bf16 [b][z][y][co][x][32c] (pre-swizzled granules),
// patch sums, voxel gather ----
__global__ void __launch_bounds__(256) k_stage(const float* __restrict__ src,
    short* __restrict__ in2, float* __restrict__ S4, float* __restrict__ Xmat,
    const int* __restrict__ inv, int vox_row_base) {
  __shared__ float tile[128][65];
  __shared__ int mcnt;
  __shared__ int mx[64];
  __shared__ int mrow[64];
  int bi = blockIdx.x;
  int b = bi >> 8, z = (bi >> 2) & 63, yp = bi & 3;
  int t = threadIdx.x;
  int zp = z >> 4, pz = z & 15;
  int cc = t & 127, xh = t >> 7;
  float part0 = 0.f, part1 = 0.f;

  for (int y0 = 0; y0 < 16; ++y0) {
    int y = yp * 16 + y0;
    __syncthreads();
    if (t == 0) mcnt = 0;
    {
      int x = t & 63, w = t >> 6;
      const float* sp = src + (long)b * 128 * 262144 + (long)z * 4096 + (long)y * 64 + x;
      #pragma unroll 4
      for (int it = 0; it < 32; ++it) {
        int c = it * 4 + w;
        tile[c][x] = sp[(long)c * 262144];
      }
    }
    __syncthreads();
    if (in2 != nullptr) {
      long rowbase = ((long)(b * 64 + z) * 64 + y) * 8192;
      int x = t >> 2, kg = t & 3;
      int slot = kg ^ ((x >> 1) & 3);
      #pragma unroll
      for (int co = 0; co < 4; ++co) {
        short8 pk;
        #pragma unroll
        for (int j = 0; j < 8; ++j) pk[j] = (short)f2bf(tile[co * 32 + kg * 8 + j][x]);
        *(short8*)(in2 + rowbase + co * 2048 + x * 32 + slot * 8) = pk;
      }
    }
    {
      float s0 = 0.f, s1 = 0.f;
      #pragma unroll
      for (int px = 0; px < 16; ++px) s0 += tile[cc][(xh * 2) * 16 + px];
      #pragma unroll
      for (int px = 0; px < 16; ++px) s1 += tile[cc][(xh * 2 + 1) * 16 + px];
      part0 += s0; part1 += s1;
    }
    if (t < 64) {
      int s = inv[pz * 256 + y0 * 16 + (t & 15)];
      if (s >= 0) {
        int idx = atomicAdd(&mcnt, 1);
        mx[idx] = t;
        int n = zp * 16 + yp * 4 + (t >> 4);
        mrow[idx] = vox_row_base + (b * 64 + n) * 100 + s;
      }
    }
    __syncthreads();
    int mc = mcnt;
    for (int i = 0; i < mc; ++i) {
      if (t < 128) Xmat[(long)mrow[i] * 128 + t] = tile[t][mx[i]];
    }
  }
  long sb = ((long)(b * 64 + z) * 4 + yp) * 512;
  S4[sb + cc * 4 + xh * 2 + 0] = part0;
  S4[sb + cc * 4 + xh * 2 + 1] = part1;
}

// ---------------- conv: double-buffered window, async stage co+1 under compute co ----
// grid 2048 (XCD-swizzled): b(2) x z(64) x yg(16); 512 threads = 8 waves.
// wave = (xh, kw, yh): 32x x 32och x 2y, K-half ks=kw. Per tap: 1 B + 2 ds_read + 2 MFMA.
// LDS: 2 windows x 18 rows x 4KB + zero row = 148 KB -> 1 block/CU.
// Stage of window co+1 (global_load_lds, async) overlaps compute of co; the
// end-of-co __syncthreads (full vmcnt drain) is the only wait.
__global__ void __launch_bounds__(512, 2) k_conv(const short* __restrict__ in2,
    const short* __restrict__ wt2, const float* __restrict__ c1b,
    const float* __restrict__ c2w, const float* __restrict__ c2b,
    const short* __restrict__ zpage, int* __restrict__ counts) {
  extern __shared__ char smem[];
  __shared__ int lcnt[4];
  int bi0 = blockIdx.x;
  int bi = ((bi0 & 7) << 8) | (bi0 >> 3);          // bijective XCD swizzle (2048 = 8*256)
  int b = bi >> 10, z = (bi >> 4) & 63, yg = bi & 15;
  int y0 = yg * 4;
  int tid = threadIdx.x;
  int lane = tid & 63;
  int l31 = lane & 31, half = lane >> 5;
  int wave = tid >> 6;
  int xh = wave & 1, kw = (wave >> 1) & 1, yh = wave >> 2;

  if (tid < 4) lcnt[tid] = 0;
  if (tid < 256) *(int4*)(smem + 147456 + tid * 16) = int4{0, 0, 0, 0};  // zero row
  int zoff = 147456 + lane * 16;

  // staging thread constants: thread covers rows wr = 2c + sr2, c=0..8
  int sr2 = tid >> 8, pos = tid & 255;

  // A-fragment lane offsets per dx (ks fixed = kw)
  int xbase = xh * 32 + l31;
  int kg = kw * 2 + half;
  bool val[3];
  int offA[3];
  #pragma unroll
  for (int d = 0; d < 3; ++d) {
    int xp = xbase + d - 1;
    val[d] = (unsigned)xp < 64u;
    int xc = min(max(xp, 0), 63);
    offA[d] = xc * 64 + ((kg ^ ((xc >> 1) & 3)) << 4);
  }

  f32x16 acc0 = {}, acc1 = {};

  // ---- stage window co=0 into buffer 0 ----
  #pragma unroll
  for (int c = 0; c < 9; ++c) {
    int wr = c * 2 + sr2;
    int zz = z - 1 + wr / 6;
    int yy = y0 - 1 + wr % 6;
    const short* g = (((unsigned)zz < 64u) && ((unsigned)yy < 64u))
        ? (in2 + ((long)((b * 64 + zz) * 64 + yy)) * 8192 + pos * 8)
        : (zpage + pos * 8);
    async_copy16(smem + wr * 4096 + pos * 16, g);
  }
  __syncthreads();   // window 0 ready

  for (int co = 0; co < 4; ++co) {
    int cur = (co & 1) * 73728;
    // ---- issue async stage of window co+1 into the other buffer ----
    if (co < 3) {
      int nxt = ((co + 1) & 1) * 73728;
      #pragma unroll
      for (int c = 0; c < 9; ++c) {
        int wr = c * 2 + sr2;
        int zz = z - 1 + wr / 6;
        int yy = y0 - 1 + wr % 6;
        const short* g = (((unsigned)zz < 64u) && ((unsigned)yy < 64u))
            ? (in2 + ((long)((b * 64 + zz) * 64 + yy)) * 8192 + (co + 1) * 2048 + pos * 8)
            : (zpage + pos * 8);
        async_copy16(smem + nxt + wr * 4096 + pos * 16, g);
      }
    }
    // ---- compute window co: 27 taps, B 2-deep rotate, 2 MFMAs per tap ----
    const short8* pB = (const short8*)wt2 + co * 3456 + kw * 64 + half * 32 + l31;
    short8 bNext = pB[0];
    #pragma unroll
    for (int tap = 0; tap < 27; ++tap) {
      short8 bCur = bNext;
      if (tap < 26) bNext = pB[(tap + 1) * 128];
      const int dz = tap / 9, r9 = tap % 9, dy = r9 / 3, dxi = r9 % 3;
      bool v = val[dxi];
      int base = cur + (dz * 6 + dy + yh * 2) * 4096 + offA[dxi];
      int ao0 = v ? base : zoff;
      int ao1 = v ? (base + 4096) : zoff;
      short8 a0 = *(const short8*)(smem + ao0);
      short8 a1 = *(const short8*)(smem + ao1);
      acc0 = __builtin_amdgcn_mfma_f32_32x32x16_bf16(a0, bCur, acc0, 0, 0, 0);
      acc1 = __builtin_amdgcn_mfma_f32_32x32x16_bf16(a1, bCur, acc1, 0, 0, 0);
    }
    __syncthreads();   // drains vmcnt -> window co+1 ready; all waves done with co
  }

  // ---- cross-kw reduction via LDS (reuses window region) ----
  float* sf = (float*)smem;
  if (kw == 1) {
    #pragma unroll
    for (int r = 0; r < 16; ++r) {
      sf[(((xh * 2 + yh) * 2 + 0) * 16 + r) * 64 + lane] = acc0[r];
      sf[(((xh * 2 + yh) * 2 + 1) * 16 + r) * 64 + lane] = acc1[r];
    }
  }
  __syncthreads();
  if (kw == 0) {
    float b1v = c1b[l31];
    float w2v = c2w[l31];
    float b2v = c2b[0];
    int cnt0 = 0, cnt1 = 0;
    #pragma unroll
    for (int yi = 0; yi < 2; ++yi) {
      #pragma unroll
      for (int r = 0; r < 16; ++r) {
        float mine = yi ? acc1[r] : acc0[r];
        float v = mine + sf[(((xh * 2 + yh) * 2 + yi) * 16 + r) * 64 + lane];
        v = fmaxf(v + b1v, 0.f) * w2v;
        v += __shfl_xor(v, 1);
        v += __shfl_xor(v, 2);
        v += __shfl_xor(v, 4);
        v += __shfl_xor(v, 8);
        v += __shfl_xor(v, 16);
        int bit = (v + b2v) > THR_LOGIT;
        if (r < 8) cnt0 += bit; else cnt1 += bit;
      }
    }
    if (l31 == 0) {
      atomicAdd(&lcnt[xh * 2 + 0], cnt0);
      atomicAdd(&lcnt[xh * 2 + 1], cnt1);
    }
  }
  __syncthreads();
  if (tid < 4) {
    int n = (z >> 4) * 16 + (yg >> 2) * 4 + tid;
    atomicAdd(&counts[b * 64 + n], lcnt[tid]);
  }
}

// ---------------- reduce S4 -> X vec rows (deterministic) ----------------
__global__ void __launch_bounds__(256) k_vecreduce(const float* __restrict__ S4a,
    const float* __restrict__ S4p, float* __restrict__ Xmat) {
  int g = blockIdx.x * 256 + threadIdx.x;   // 32768
  int ten = g >> 14, rem = g & 16383;
  int b = rem >> 13, n = (rem >> 7) & 63, c = rem & 127;
  int zp = n >> 4, yp = (n >> 2) & 3, xp = n & 3;
  const float* S = ten ? S4p : S4a;
  float s = 0.f;
  #pragma unroll
  for (int k = 0; k < 16; ++k)
    s += S[((long)(b * 64 + zp * 16 + k) * 4 + yp) * 512 + c * 4 + xp];
  Xmat[(long)(ten * 128 + b * 64 + n) * 128 + c] = s * (1.f / 4096.f);
}

// ---------------- projector MLP + normalize ----------------
__global__ void __launch_bounds__(256) k_proj(const float* __restrict__ Xmat,
    const float* __restrict__ w1t, const float* __restrict__ pb1,
    const float* __restrict__ w2t, const float* __restrict__ pb2,
    float* __restrict__ P) {
  __shared__ float xsT[128][20];
  __shared__ float hsT[128][20];
  __shared__ float os[16][68];
  int bi = blockIdx.x;
  long row0 = (long)bi * 16;
  int t = threadIdx.x;
  {
    int r = t >> 4, c0 = (t & 15) * 8;
    const float* xp = Xmat + (row0 + r) * 128 + c0;
    #pragma unroll
    for (int k = 0; k < 8; ++k) xsT[c0 + k][r] = xp[k];
  }
  __syncthreads();
  {
    int j = t & 127, rh = t >> 7;
    float hacc[8];
    float bb = pb1[j];
    #pragma unroll
    for (int r8 = 0; r8 < 8; ++r8) hacc[r8] = bb;
    for (int c = 0; c < 128; ++c) {
      float w = w1t[c * 128 + j];
      float4 xlo = *(const float4*)&xsT[c][rh * 8];
      float4 xhi = *(const float4*)&xsT[c][rh * 8 + 4];
      hacc[0] += xlo.x * w; hacc[1] += xlo.y * w; hacc[2] += xlo.z * w; hacc[3] += xlo.w * w;
      hacc[4] += xhi.x * w; hacc[5] += xhi.y * w; hacc[6] += xhi.z * w; hacc[7] += xhi.w * w;
    }
    #pragma unroll
    for (int r8 = 0; r8 < 8; ++r8) hsT[j][rh * 8 + r8] = fmaxf(hacc[r8], 0.f);
  }
  __syncthreads();
  {
    int d = t & 63, rq = t >> 6;
    float oacc[4];
    float bb = pb2[d];
    #pragma unroll
    for (int r4 = 0; r4 < 4; ++r4) oacc[r4] = bb;
    for (int j = 0; j < 128; ++j) {
      float w = w2t[j * 64 + d];
      float4 hv = *(const float4*)&hsT[j][rq * 4];
      oacc[0] += hv.x * w; oacc[1] += hv.y * w; oacc[2] += hv.z * w; oacc[3] += hv.w * w;
    }
    #pragma unroll
    for (int r4 = 0; r4 < 4; ++r4) os[rq * 4 + r4][d] = oacc[r4];
  }
  __syncthreads();
  {
    int r = t >> 4, dg = t & 15;
    float4 v = *(const float4*)&os[r][dg * 4];
    float ss = v.x * v.x + v.y * v.y + v.z * v.z + v.w * v.w;
    ss += __shfl_xor(ss, 1); ss += __shfl_xor(ss, 2);
    ss += __shfl_xor(ss, 4); ss += __shfl_xor(ss, 8);
    float sc = 1.f / fmaxf(sqrtf(ss), 1e-12f);
    float4 o; o.x = v.x * sc; o.y = v.y * sc; o.z = v.z * sc; o.w = v.w * sc;
    *(float4*)&P[(row0 + r) * 64 + dg * 4] = o;
  }
}

// ---------------- sim + logsumexp per (b,n) ----------------
__global__ void __launch_bounds__(128) k_sim(const float* __restrict__ P,
                                             float* __restrict__ vloss) {
  __shared__ float ps[100][68];
  __shared__ float red[128];
  int bn = blockIdx.x;
  int t = threadIdx.x;
  long pbase = (long)(13056 + bn * 100) * 64;
  for (int i = t; i < 1600; i += 128) {
    int r = i >> 4, dg = i & 15;
    *(float4*)&ps[r][dg * 4] = *(const float4*)&P[pbase + r * 64 + dg * 4];
  }
  float4 areg[16];
  long abase = (long)(256 + bn * 100) * 64;
  if (t < 100) {
    #pragma unroll
    for (int j = 0; j < 16; ++j) areg[j] = *(const float4*)&P[abase + (long)t * 64 + j * 4];
  }
  __syncthreads();
  float res = 0.f;
  if (t < 100) {
    float m = -1e30f, sum = 0.f, diag = 0.f;
    for (int t2 = 0; t2 < 100; ++t2) {
      float d = 0.f;
      #pragma unroll
      for (int j = 0; j < 16; ++j) {
        float4 pv = *(const float4*)&ps[t2][j * 4];
        d += areg[j].x * pv.x + areg[j].y * pv.y + areg[j].z * pv.z + areg[j].w * pv.w;
      }
      float sim = d * 10.f;
      if (t2 == t) diag = sim;
      float nm = fmaxf(m, sim);
      sum = sum * __expf(m - nm) + __expf(sim - nm);
      m = nm;
    }
    res = m + logf(sum) - diag;
  }
  red[t] = res;
  __syncthreads();
  if (t == 0) {
    float s = 0.f;
    for (int i = 0; i < 100; ++i) s += red[i];
    vloss[bn] = s * 0.01f;
  }
}

// ---------------- final weighted reduction ----------------
__global__ void __launch_bounds__(128) k_final(const float* __restrict__ P,
    const float* __restrict__ vloss, const int* __restrict__ counts,
    const float* __restrict__ lw, float* __restrict__ out) {
  int t = threadIdx.x;
  int lane = t & 63;
  float pterm = 0.f, vterm = 0.f; int vcnt = 0;
  {
    int c = counts[t];
    bool maskv = c >= 2458;   // ratio > 0.6
    bool maskp = c <= 1638;   // ratio < 0.4
    float d = 0.f;
    for (int k = 0; k < 64; ++k) d += P[t * 64 + k] * P[(128 + t) * 64 + k];
    if (maskp) { pterm = -d * 10.f; vcnt += 1; }
    if (maskv) { vterm = vloss[t];  vcnt += 1; }
  }
  for (int m = 1; m < 64; m <<= 1) {
    pterm += __shfl_xor(pterm, m);
    vterm += __shfl_xor(vterm, m);
    vcnt  += __shfl_xor(vcnt, m);
  }
  __shared__ float sp[2], sv[2]; __shared__ int sc[2];
  if (lane == 0) { sp[t >> 6] = pterm; sv[t >> 6] = vterm; sc[t >> 6] = vcnt; }
  __syncthreads();
  if (t == 0) {
    float psum = sp[0] + sp[1], vsum = sv[0] + sv[1];
    int vc = sc[0] + sc[1];
    float total = lw[0] * psum + lw[1] * vsum;
    out[0] = (vc > 0) ? total / (float)vc : 0.f;
  }
}

// ---------------- launch ----------------
extern "C" void kernel_launch(void* const* d_in, const int* in_sizes, int n_in,
                              void* d_out, int out_size, void* d_ws, size_t ws_size,
                              hipStream_t stream) {
  const float* anchor   = (const float*)d_in[0];
  const float* positive = (const float*)d_in[1];
  const float* c1w = (const float*)d_in[2];
  const float* c1b = (const float*)d_in[3];
  const float* c2w = (const float*)d_in[4];
  const float* c2b = (const float*)d_in[5];
  const float* pw1 = (const float*)d_in[6];
  const float* pb1 = (const float*)d_in[7];
  const float* pw2 = (const float*)d_in[8];
  const float* pb2 = (const float*)d_in[9];
  const float* lw  = (const float*)d_in[10];
  const int*   vidx = (const int*)d_in[11];

  char* ws = (char*)d_ws;
  short* in2   = (short*)(ws + 0);                 // 134,217,728
  float* S4a   = (float*)(ws + 134217728);         // 1,048,576
  float* S4p   = (float*)(ws + 135266304);         // 1,048,576
  float* X     = (float*)(ws + 136314880);         // 13,238,272
  float* P     = (float*)(ws + 149553152);         // 6,619,136
  short* wt2   = (short*)(ws + 156172288);         // 221,184
  float* w1t   = (float*)(ws + 156393472);         // 65,536
  float* w2t   = (float*)(ws + 156459008);         // 32,768
  int*   inv   = (int*)  (ws + 156491776);         // 16,384
  int*   counts= (int*)  (ws + 156508160);         // 512
  float* vloss = (float*)(ws + 156508672);         // 512
  short* zpage = (short*)(ws + 156509184);         // 16,384 (zero page for OOB staging)

  hipFuncSetAttribute(reinterpret_cast<const void*>(k_conv),
                      hipFuncAttributeMaxDynamicSharedMemorySize, 151552);

  hipMemsetAsync(counts, 0, 128 * sizeof(int), stream);
  hipMemsetAsync(zpage, 0, 16384, stream);
  k_prep<<<528, 256, 0, stream>>>(c1w, pw1, pw2, wt2, w1t, w2t);
  k_inv<<<1, 256, 0, stream>>>(vidx, inv);
  k_stage<<<512, 256, 0, stream>>>(anchor,   in2,     S4a, X, inv, 256);
  k_stage<<<512, 256, 0, stream>>>(positive, nullptr, S4p, X, inv, 13056);
  k_conv<<<2048, 512, 151552, stream>>>(in2, wt2, c1b, c2w, c2b, zpage, counts);
  k_vecreduce<<<128, 256, 0, stream>>>(S4a, S4p, X);
  k_proj<<<1616, 256, 0, stream>>>(X, w1t, pb1, w2t, pb2, P);
  k_sim<<<128, 128, 0, stream>>>(P, vloss);
  k_final<<<1, 128, 0, stream>>>(P, vloss, counts, lw, (float*)d_out);
}

// Round 9
// 430.468 us; speedup vs baseline: 1.4364x; 1.0853x over previous
//
#include <hip/hip_runtime.h>

using short8 = __attribute__((ext_vector_type(8))) short;
using f32x16 = __attribute__((ext_vector_type(16))) float;

#define THR_LOGIT (-1.0986122886681098f)   // ln(1/3): sigmoid(x)>0.25 <=> x>ln(1/3)

__device__ __forceinline__ unsigned short f2bf(float f) {
  unsigned u = __float_as_uint(f);
  u = (u + 0x7FFFu + ((u >> 16) & 1u)) >> 16;   // RNE
  return (unsigned short)u;
}

__device__ __forceinline__ void async_copy16(void* lds, const void* g) {
  __builtin_amdgcn_global_load_lds(
      (const __attribute__((address_space(1))) unsigned int*)g,
      (__attribute__((address_space(3))) unsigned int*)lds, 16, 0, 0);
}

// ---------------- prep: weight transposes ----------------
// wt2: [co8(8)][tap(27)][half(2)][l31(32)][8c] bf16 (110592 shorts)
//   och = l31, in-ch c = co8*16 + half*8 + j8
__global__ void __launch_bounds__(256) k_prep(const float* __restrict__ c1w,
    const float* __restrict__ pw1, const float* __restrict__ pw2,
    short* __restrict__ wt2, float* __restrict__ w1t, float* __restrict__ w2t) {
  int i = blockIdx.x * 256 + threadIdx.x;
  if (i < 110592) {
    int j8 = i & 7, l31v = (i >> 3) & 31, halfv = (i >> 8) & 1;
    int tapco = i >> 9;                  // 0..215
    int tap = tapco % 27, co8 = tapco / 27;
    int c = co8 * 16 + halfv * 8 + j8;
    wt2[i] = (short)f2bf(c1w[l31v * 3456 + c * 27 + tap]);
  } else if (i < 126976) {
    int i2 = i - 110592; int c = i2 >> 7; int j = i2 & 127;
    w1t[i2] = pw1[j * 128 + c];
  } else if (i < 135168) {
    int i3 = i - 126976; int j = i3 >> 6; int d = i3 & 63;
    w2t[i3] = pw2[d * 128 + j];
  }
}

__global__ void k_inv(const int* __restrict__ vidx, int* __restrict__ inv) {
  int t = threadIdx.x;
  for (int k = t; k < 4096; k += 256) inv[k] = -1;
  __syncthreads();
  if (t < 100) inv[vidx[t]] = t;
}

// ---------------- stage: transpose->bf16 [b][z][y][co8(8)][x][16c] (pre-swizzled),
// patch sums, voxel gather ----
// granule (x, half): slot = half ^ ((x>>2)&1) within the 2KB co8-row.
__global__ void __launch_bounds__(256) k_stage(const float* __restrict__ src,
    short* __restrict__ in2, float* __restrict__ S4, float* __restrict__ Xmat,
    const int* __restrict__ inv, int vox_row_base) {
  __shared__ float tile[128][65];
  __shared__ int mcnt;
  __shared__ int mx[64];
  __shared__ int mrow[64];
  int bi = blockIdx.x;
  int b = bi >> 8, z = (bi >> 2) & 63, yp = bi & 3;
  int t = threadIdx.x;
  int zp = z >> 4, pz = z & 15;
  int cc = t & 127, xh = t >> 7;
  float part0 = 0.f, part1 = 0.f;

  for (int y0 = 0; y0 < 16; ++y0) {
    int y = yp * 16 + y0;
    __syncthreads();
    if (t == 0) mcnt = 0;
    {
      int x = t & 63, w = t >> 6;
      const float* sp = src + (long)b * 128 * 262144 + (long)z * 4096 + (long)y * 64 + x;
      #pragma unroll 4
      for (int it = 0; it < 32; ++it) {
        int c = it * 4 + w;
        tile[c][x] = sp[(long)c * 262144];
      }
    }
    __syncthreads();
    if (in2 != nullptr) {
      long rowbase = ((long)(b * 64 + z) * 64 + y) * 8192;
      int x = t >> 2, q = t & 3;
      int slot = (q & 1) ^ ((x >> 2) & 1);
      #pragma unroll
      for (int i = 0; i < 4; ++i) {
        int co8 = i * 2 + (q >> 1);
        short8 pk;
        #pragma unroll
        for (int j = 0; j < 8; ++j) pk[j] = (short)f2bf(tile[i * 32 + q * 8 + j][x]);
        *(short8*)(in2 + rowbase + co8 * 1024 + x * 16 + slot * 8) = pk;
      }
    }
    {
      float s0 = 0.f, s1 = 0.f;
      #pragma unroll
      for (int px = 0; px < 16; ++px) s0 += tile[cc][(xh * 2) * 16 + px];
      #pragma unroll
      for (int px = 0; px < 16; ++px) s1 += tile[cc][(xh * 2 + 1) * 16 + px];
      part0 += s0; part1 += s1;
    }
    if (t < 64) {
      int s = inv[pz * 256 + y0 * 16 + (t & 15)];
      if (s >= 0) {
        int idx = atomicAdd(&mcnt, 1);
        mx[idx] = t;
        int n = zp * 16 + yp * 4 + (t >> 4);
        mrow[idx] = vox_row_base + (b * 64 + n) * 100 + s;
      }
    }
    __syncthreads();
    int mc = mcnt;
    for (int i = 0; i < mc; ++i) {
      if (t < 128) Xmat[(long)mrow[i] * 128 + t] = tile[t][mx[i]];
    }
  }
  long sb = ((long)(b * 64 + z) * 4 + yp) * 512;
  S4[sb + cc * 4 + xh * 2 + 0] = part0;
  S4[sb + cc * 4 + xh * 2 + 1] = part1;
}

// ---------------- conv: 16-ch chunks, double-buffered async window, 2 blocks/CU ----
// grid 2048 (XCD-swizzled): b(2) x z(64) x yg(16); 512 threads = 8 waves.
// wave = (xh, yo): 32x x 32och x 1y. Per tap: 1 B(rotate) + 1 ds_read_b128 + 1 MFMA.
// 8 co8 passes of 16 in-ch. LDS: 2 x (18 rows x 2KB) + 1KB zero = 73 KB -> 2 blocks/CU.
// Window co8+1 staged via async global_load_lds under compute of co8 (T14).
__global__ void __launch_bounds__(512, 2) k_conv(const short* __restrict__ in2,
    const short* __restrict__ wt2, const float* __restrict__ c1b,
    const float* __restrict__ c2w, const float* __restrict__ c2b,
    const short* __restrict__ zpage, int* __restrict__ counts) {
  extern __shared__ char smem[];
  __shared__ int lcnt[4];
  int bi0 = blockIdx.x;
  int bi = ((bi0 & 7) << 8) | (bi0 >> 3);          // bijective XCD swizzle (2048 = 8*256)
  int b = bi >> 10, z = (bi >> 4) & 63, yg = bi & 15;
  int y0 = yg * 4;
  int tid = threadIdx.x;
  int lane = tid & 63;
  int l31 = lane & 31, half = lane >> 5;
  int wave = tid >> 6;
  int xh = wave & 1, yo = wave >> 1;               // yo 0..3

  if (tid < 4) lcnt[tid] = 0;
  if (tid < 64) *(int4*)(smem + 73728 + tid * 16) = int4{0, 0, 0, 0};  // zero row (1KB)
  int zoff = 73728 + lane * 16;

  // A-fragment lane offsets per dx
  int xbase = xh * 32 + l31;
  bool val[3];
  int offA[3];
  #pragma unroll
  for (int d = 0; d < 3; ++d) {
    int xp = xbase + d - 1;
    val[d] = (unsigned)xp < 64u;
    int xc = min(max(xp, 0), 63);
    offA[d] = xc * 32 + ((half ^ ((xc >> 2) & 1)) << 4);
  }

  f32x16 acc = {};

  // ---- stage window co8=0 into buffer 0 (2304 granules of 16B) ----
  #pragma unroll
  for (int c = 0; c < 4; ++c) {
    int g = c * 512 + tid;
    int wr = g >> 7, pos = g & 127;
    int zz = z - 1 + wr / 6, yy = y0 - 1 + wr % 6;
    const short* gp = (((unsigned)zz < 64u) && ((unsigned)yy < 64u))
        ? (in2 + ((long)((b * 64 + zz) * 64 + yy)) * 8192 + pos * 8)
        : (zpage + pos * 8);
    async_copy16(smem + g * 16, gp);
  }
  if (tid < 256) {
    int g = 2048 + tid;
    int wr = g >> 7, pos = g & 127;
    int zz = z - 1 + wr / 6, yy = y0 - 1 + wr % 6;
    const short* gp = (((unsigned)zz < 64u) && ((unsigned)yy < 64u))
        ? (in2 + ((long)((b * 64 + zz) * 64 + yy)) * 8192 + pos * 8)
        : (zpage + pos * 8);
    async_copy16(smem + g * 16, gp);
  }
  __syncthreads();   // window 0 ready

  for (int co8 = 0; co8 < 8; ++co8) {
    int cur = (co8 & 1) * 36864;
    // ---- issue async stage of window co8+1 into the other buffer ----
    if (co8 < 7) {
      int nxt = 36864 - cur;
      int gofs = (co8 + 1) * 1024;
      #pragma unroll
      for (int c = 0; c < 4; ++c) {
        int g = c * 512 + tid;
        int wr = g >> 7, pos = g & 127;
        int zz = z - 1 + wr / 6, yy = y0 - 1 + wr % 6;
        const short* gp = (((unsigned)zz < 64u) && ((unsigned)yy < 64u))
            ? (in2 + ((long)((b * 64 + zz) * 64 + yy)) * 8192 + gofs + pos * 8)
            : (zpage + pos * 8);
        async_copy16(smem + nxt + g * 16, gp);
      }
      if (tid < 256) {
        int g = 2048 + tid;
        int wr = g >> 7, pos = g & 127;
        int zz = z - 1 + wr / 6, yy = y0 - 1 + wr % 6;
        const short* gp = (((unsigned)zz < 64u) && ((unsigned)yy < 64u))
            ? (in2 + ((long)((b * 64 + zz) * 64 + yy)) * 8192 + gofs + pos * 8)
            : (zpage + pos * 8);
        async_copy16(smem + nxt + g * 16, gp);
      }
    }
    // ---- compute window co8: 27 taps, B 2-deep rotate, 1 MFMA/tap ----
    const short8* pB0 = (const short8*)wt2 + ((co8 * 27) * 2 + half) * 32 + l31;
    short8 bNext = pB0[0];
    #pragma unroll
    for (int tap = 0; tap < 27; ++tap) {
      short8 bCur = bNext;
      if (tap < 26) bNext = pB0[(tap + 1) * 64];
      const int dz = tap / 9, r9 = tap % 9, dy = r9 / 3, dxi = r9 % 3;
      int base = cur + (dz * 6 + dy + yo) * 2048 + offA[dxi];
      int ao = val[dxi] ? base : zoff;
      short8 a = *(const short8*)(smem + ao);
      acc = __builtin_amdgcn_mfma_f32_32x32x16_bf16(a, bCur, acc, 0, 0, 0);
    }
    __syncthreads();   // drains staging vmcnt; all waves done with cur
  }

  // ---- epilogue: relu, 1x1, och-reduce, threshold, patch counts ----
  float b1v = c1b[l31];
  float w2v = c2w[l31];
  float b2v = c2b[0];
  int cnt0 = 0, cnt1 = 0;
  #pragma unroll
  for (int r = 0; r < 16; ++r) {
    float v = fmaxf(acc[r] + b1v, 0.f) * w2v;
    v += __shfl_xor(v, 1);
    v += __shfl_xor(v, 2);
    v += __shfl_xor(v, 4);
    v += __shfl_xor(v, 8);
    v += __shfl_xor(v, 16);
    int bit = (v + b2v) > THR_LOGIT;
    if (r < 8) cnt0 += bit; else cnt1 += bit;     // row<16 <=> r<8 (x-patch local)
  }
  if (l31 == 0) {                                  // lanes 0 and 32: disjoint row sets
    atomicAdd(&lcnt[xh * 2 + 0], cnt0);
    atomicAdd(&lcnt[xh * 2 + 1], cnt1);
  }
  __syncthreads();
  if (tid < 4) {
    int n = (z >> 4) * 16 + (yg >> 2) * 4 + tid;
    atomicAdd(&counts[b * 64 + n], lcnt[tid]);
  }
}

// ---------------- reduce S4 -> X vec rows (deterministic) ----------------
__global__ void __launch_bounds__(256) k_vecreduce(const float* __restrict__ S4a,
    const float* __restrict__ S4p, float* __restrict__ Xmat) {
  int g = blockIdx.x * 256 + threadIdx.x;   // 32768
  int ten = g >> 14, rem = g & 16383;
  int b = rem >> 13, n = (rem >> 7) & 63, c = rem & 127;
  int zp = n >> 4, yp = (n >> 2) & 3, xp = n & 3;
  const float* S = ten ? S4p : S4a;
  float s = 0.f;
  #pragma unroll
  for (int k = 0; k < 16; ++k)
    s += S[((long)(b * 64 + zp * 16 + k) * 4 + yp) * 512 + c * 4 + xp];
  Xmat[(long)(ten * 128 + b * 64 + n) * 128 + c] = s * (1.f / 4096.f);
}

// ---------------- projector MLP + normalize ----------------
__global__ void __launch_bounds__(256) k_proj(const float* __restrict__ Xmat,
    const float* __restrict__ w1t, const float* __restrict__ pb1,
    const float* __restrict__ w2t, const float* __restrict__ pb2,
    float* __restrict__ P) {
  __shared__ float xsT[128][20];
  __shared__ float hsT[128][20];
  __shared__ float os[16][68];
  int bi = blockIdx.x;
  long row0 = (long)bi * 16;
  int t = threadIdx.x;
  {
    int r = t >> 4, c0 = (t & 15) * 8;
    const float* xp = Xmat + (row0 + r) * 128 + c0;
    #pragma unroll
    for (int k = 0; k < 8; ++k) xsT[c0 + k][r] = xp[k];
  }
  __syncthreads();
  {
    int j = t & 127, rh = t >> 7;
    float hacc[8];
    float bb = pb1[j];
    #pragma unroll
    for (int r8 = 0; r8 < 8; ++r8) hacc[r8] = bb;
    for (int c = 0; c < 128; ++c) {
      float w = w1t[c * 128 + j];
      float4 xlo = *(const float4*)&xsT[c][rh * 8];
      float4 xhi = *(const float4*)&xsT[c][rh * 8 + 4];
      hacc[0] += xlo.x * w; hacc[1] += xlo.y * w; hacc[2] += xlo.z * w; hacc[3] += xlo.w * w;
      hacc[4] += xhi.x * w; hacc[5] += xhi.y * w; hacc[6] += xhi.z * w; hacc[7] += xhi.w * w;
    }
    #pragma unroll
    for (int r8 = 0; r8 < 8; ++r8) hsT[j][rh * 8 + r8] = fmaxf(hacc[r8], 0.f);
  }
  __syncthreads();
  {
    int d = t & 63, rq = t >> 6;
    float oacc[4];
    float bb = pb2[d];
    #pragma unroll
    for (int r4 = 0; r4 < 4; ++r4) oacc[r4] = bb;
    for (int j = 0; j < 128; ++j) {
      float w = w2t[j * 64 + d];
      float4 hv = *(const float4*)&hsT[j][rq * 4];
      oacc[0] += hv.x * w; oacc[1] += hv.y * w; oacc[2] += hv.z * w; oacc[3] += hv.w * w;
    }
    #pragma unroll
    for (int r4 = 0; r4 < 4; ++r4) os[rq * 4 + r4][d] = oacc[r4];
  }
  __syncthreads();
  {
    int r = t >> 4, dg = t & 15;
    float4 v = *(const float4*)&os[r][dg * 4];
    float ss = v.x * v.x + v.y * v.y + v.z * v.z + v.w * v.w;
    ss += __shfl_xor(ss, 1); ss += __shfl_xor(ss, 2);
    ss += __shfl_xor(ss, 4); ss += __shfl_xor(ss, 8);
    float sc = 1.f / fmaxf(sqrtf(ss), 1e-12f);
    float4 o; o.x = v.x * sc; o.y = v.y * sc; o.z = v.z * sc; o.w = v.w * sc;
    *(float4*)&P[(row0 + r) * 64 + dg * 4] = o;
  }
}

// ---------------- sim + logsumexp per (b,n) ----------------
__global__ void __launch_bounds__(128) k_sim(const float* __restrict__ P,
                                             float* __restrict__ vloss) {
  __shared__ float ps[100][68];
  __shared__ float red[128];
  int bn = blockIdx.x;
  int t = threadIdx.x;
  long pbase = (long)(13056 + bn * 100) * 64;
  for (int i = t; i < 1600; i += 128) {
    int r = i >> 4, dg = i & 15;
    *(float4*)&ps[r][dg * 4] = *(const float4*)&P[pbase + r * 64 + dg * 4];
  }
  float4 areg[16];
  long abase = (long)(256 + bn * 100) * 64;
  if (t < 100) {
    #pragma unroll
    for (int j = 0; j < 16; ++j) areg[j] = *(const float4*)&P[abase + (long)t * 64 + j * 4];
  }
  __syncthreads();
  float res = 0.f;
  if (t < 100) {
    float m = -1e30f, sum = 0.f, diag = 0.f;
    for (int t2 = 0; t2 < 100; ++t2) {
      float d = 0.f;
      #pragma unroll
      for (int j = 0; j < 16; ++j) {
        float4 pv = *(const float4*)&ps[t2][j * 4];
        d += areg[j].x * pv.x + areg[j].y * pv.y + areg[j].z * pv.z + areg[j].w * pv.w;
      }
      float sim = d * 10.f;
      if (t2 == t) diag = sim;
      float nm = fmaxf(m, sim);
      sum = sum * __expf(m - nm) + __expf(sim - nm);
      m = nm;
    }
    res = m + logf(sum) - diag;
  }
  red[t] = res;
  __syncthreads();
  if (t == 0) {
    float s = 0.f;
    for (int i = 0; i < 100; ++i) s += red[i];
    vloss[bn] = s * 0.01f;
  }
}

// ---------------- final weighted reduction ----------------
__global__ void __launch_bounds__(128) k_final(const float* __restrict__ P,
    const float* __restrict__ vloss, const int* __restrict__ counts,
    const float* __restrict__ lw, float* __restrict__ out) {
  int t = threadIdx.x;
  int lane = t & 63;
  float pterm = 0.f, vterm = 0.f; int vcnt = 0;
  {
    int c = counts[t];
    bool maskv = c >= 2458;   // ratio > 0.6
    bool maskp = c <= 1638;   // ratio < 0.4
    float d = 0.f;
    for (int k = 0; k < 64; ++k) d += P[t * 64 + k] * P[(128 + t) * 64 + k];
    if (maskp) { pterm = -d * 10.f; vcnt += 1; }
    if (maskv) { vterm = vloss[t];  vcnt += 1; }
  }
  for (int m = 1; m < 64; m <<= 1) {
    pterm += __shfl_xor(pterm, m);
    vterm += __shfl_xor(vterm, m);
    vcnt  += __shfl_xor(vcnt, m);
  }
  __shared__ float sp[2], sv[2]; __shared__ int sc[2];
  if (lane == 0) { sp[t >> 6] = pterm; sv[t >> 6] = vterm; sc[t >> 6] = vcnt; }
  __syncthreads();
  if (t == 0) {
    float psum = sp[0] + sp[1], vsum = sv[0] + sv[1];
    int vc = sc[0] + sc[1];
    float total = lw[0] * psum + lw[1] * vsum;
    out[0] = (vc > 0) ? total / (float)vc : 0.f;
  }
}

// ---------------- launch ----------------
extern "C" void kernel_launch(void* const* d_in, const int* in_sizes, int n_in,
                              void* d_out, int out_size, void* d_ws, size_t ws_size,
                              hipStream_t stream) {
  const float* anchor   = (const float*)d_in[0];
  const float* positive = (const float*)d_in[1];
  const float* c1w = (const float*)d_in[2];
  const float* c1b = (const float*)d_in[3];
  const float* c2w = (const float*)d_in[4];
  const float* c2b = (const float*)d_in[5];
  const float* pw1 = (const float*)d_in[6];
  const float* pb1 = (const float*)d_in[7];
  const float* pw2 = (const float*)d_in[8];
  const float* pb2 = (const float*)d_in[9];
  const float* lw  = (const float*)d_in[10];
  const int*   vidx = (const int*)d_in[11];

  char* ws = (char*)d_ws;
  short* in2   = (short*)(ws + 0);                 // 134,217,728
  float* S4a   = (float*)(ws + 134217728);         // 1,048,576
  float* S4p   = (float*)(ws + 135266304);         // 1,048,576
  float* X     = (float*)(ws + 136314880);         // 13,238,272
  float* P     = (float*)(ws + 149553152);         // 6,619,136
  short* wt2   = (short*)(ws + 156172288);         // 221,184
  float* w1t   = (float*)(ws + 156393472);         // 65,536
  float* w2t   = (float*)(ws + 156459008);         // 32,768
  int*   inv   = (int*)  (ws + 156491776);         // 16,384
  int*   counts= (int*)  (ws + 156508160);         // 512
  float* vloss = (float*)(ws + 156508672);         // 512
  short* zpage = (short*)(ws + 156509184);         // 16,384 (zero page for OOB staging)

  hipFuncSetAttribute(reinterpret_cast<const void*>(k_conv),
                      hipFuncAttributeMaxDynamicSharedMemorySize, 74752);

  hipMemsetAsync(counts, 0, 128 * sizeof(int), stream);
  hipMemsetAsync(zpage, 0, 16384, stream);
  k_prep<<<528, 256, 0, stream>>>(c1w, pw1, pw2, wt2, w1t, w2t);
  k_inv<<<1, 256, 0, stream>>>(vidx, inv);
  k_stage<<<512, 256, 0, stream>>>(anchor,   in2,     S4a, X, inv, 256);
  k_stage<<<512, 256, 0, stream>>>(positive, nullptr, S4p, X, inv, 13056);
  k_conv<<<2048, 512, 74752, stream>>>(in2, wt2, c1b, c2w, c2b, zpage, counts);
  k_vecreduce<<<128, 256, 0, stream>>>(S4a, S4p, X);
  k_proj<<<1616, 256, 0, stream>>>(X, w1t, pb1, w2t, pb2, P);
  k_sim<<<128, 128, 0, stream>>>(P, vloss);
  k_final<<<1, 128, 0, stream>>>(P, vloss, counts, lw, (float*)d_out);
}